// Round 12
// baseline (416.206 us; speedup 1.0000x reference)
//
#include <hip/hip_runtime.h>

#define NN 16384      // nodes
#define NE 65536      // edges
#define NT 81920      // edges + self loops
#define NG 512        // graphs
#define NH 10         // heads
#define FX 78         // features per head
#define HD 780        // hidden = NH*FX
#define SEQ 1000
#define EMB 100
#define NF 32
#define KS 8
#define CLEN 93

typedef __bf16 bf16x8 __attribute__((ext_vector_type(8)));
typedef float  f32x4  __attribute__((ext_vector_type(4)));

__device__ inline void load_lds16(const void* g, void* l)
{
    __builtin_amdgcn_global_load_lds(
        (const __attribute__((address_space(1))) void*)g,
        (__attribute__((address_space(3))) void*)l, 16, 0, 0);
}

// ---------------------------------------------------------------------------
// preproc: emb cast, conv W' repack, x cast, goffs (all coalesced-friendly)
// ---------------------------------------------------------------------------
__global__ __launch_bounds__(256)
void preproc_all(const float* __restrict__ emb_w, __bf16* __restrict__ embbf,
                 const float* __restrict__ conv_w, __bf16* __restrict__ w2,
                 const float* __restrict__ x, __bf16* __restrict__ Abf,
                 const int* __restrict__ batch, int* __restrict__ goffs)
{
    long idx = (long)blockIdx.x*256 + threadIdx.x;
    if (idx < 896112L) {
        int r = idx / 112, c = idx - (long)(idx/112)*112;
        embbf[idx] = (__bf16)((r < 8000 && c < EMB) ? emb_w[(size_t)r*EMB + c] : 0.f);
        return;
    }
    idx -= 896112L;
    if (idx < 262144L) {
        int op = idx >> 10, i = idx & 1023;
        int o = op & 31, k = op >> 5;
        w2[idx] = (i < SEQ) ? (__bf16)conv_w[((size_t)o*SEQ + i)*KS + k] : (__bf16)0.f;
        return;
    }
    idx -= 262144L;
    if (idx < 1572864L) {
        int r = idx / 96, c = idx - (long)(idx/96)*96;
        Abf[idx] = (c < FX) ? (__bf16)x[(size_t)r*FX + c] : (__bf16)0.f;
        return;
    }
    idx -= 1572864L;
    if (idx <= NG) {
        int b = (int)idx;
        if (b == NG) { goffs[NG] = NN; return; }
        int lo = 0, hi = NN;
        while (lo < hi) { int mid = (lo+hi) >> 1; if (batch[mid] < b) lo = mid+1; else hi = mid; }
        goffs[b] = lo;
    }
}
#define PRE_TOTAL 2731633L
#define PRE_BLOCKS ((PRE_TOTAL + 255) / 256)

// ---------------------------------------------------------------------------
// LDS-tiled transpose+cast for all FC/GNN weights: out[n][k] = (bf16)B[k][n],
// zero-padded to [Np][Kp]. One block = one 32x32 tile; both sides coalesced.
// ---------------------------------------------------------------------------
__global__ __launch_bounds__(256)
void transpose_w(const float* __restrict__ fcg1_w, __bf16* __restrict__ wg1,
                 const float* __restrict__ gcn_w,  __bf16* __restrict__ wgcn,
                 const float* __restrict__ gat_w,  __bf16* __restrict__ wgat,
                 const float* __restrict__ fcg2_w, __bf16* __restrict__ wg2,
                 const float* __restrict__ fcxt_w, __bf16* __restrict__ wxt,
                 const float* __restrict__ mlp1_w, __bf16* __restrict__ wm1,
                 const float* __restrict__ mlp2_w, __bf16* __restrict__ wm2)
{
    __shared__ float tile[32][33];
    int t = blockIdx.x;
    const float* B; __bf16* out; int K, N, Kp, tk_n;
    if (t < 2352)              { B=fcg1_w; out=wg1;  K=1560; N=1500; Kp=1568; tk_n=49; }
    else if ((t -= 2352) < 700){ B=gcn_w;  out=wgcn; K=780;  N=780;  Kp=800;  tk_n=25; }
    else if ((t -= 700) < 84)  { B=gat_w;  out=wgat; K=78;   N=780;  Kp=96;   tk_n=3;  }
    else if ((t -= 84) < 188)  { B=fcg2_w; out=wg2;  K=1500; N=128;  Kp=1504; tk_n=47; }
    else if ((t -= 188) < 372) { B=fcxt_w; out=wxt;  K=2976; N=128;  Kp=2976; tk_n=93; }
    else if ((t -= 372) < 256) { B=mlp1_w; out=wm1;  K=256;  N=1024; Kp=256;  tk_n=8;  }
    else { t -= 256;             B=mlp2_w; out=wm2;  K=1024; N=512;  Kp=1024; tk_n=32; }
    int k0 = (t % tk_n) * 32, n0 = (t / tk_n) * 32;
    int jj = threadIdx.x & 31, ii0 = threadIdx.x >> 5;
#pragma unroll
    for (int g = 0; g < 4; g++) {
        int i = ii0 + g*8;
        int gk = k0 + i, gn = n0 + jj;
        tile[i][jj] = (gk < K && gn < N) ? B[(size_t)gk*N + gn] : 0.f;
    }
    __syncthreads();
#pragma unroll
    for (int g = 0; g < 4; g++) {
        int i = ii0 + g*8;
        out[(size_t)(n0 + i)*Kp + k0 + jj] = (__bf16)tile[jj][i];
    }
}
#define TRANS_BLOCKS 4464

// ---------------------------------------------------------------------------
// bf16 MFMA GEMM (full-K): 8 waves, 128x128 tile, wave = 32x64 subtile.
// global_load_lds(16B) staging, linear [128][32] LDS, XCD bijective swizzle.
// ---------------------------------------------------------------------------
template<bool BIAS, bool RELU, bool BF16OUT>
__global__ __launch_bounds__(512)
void gemm_mfma(const __bf16* __restrict__ A, const __bf16* __restrict__ Bt,
               const float* __restrict__ bias, void* __restrict__ Cv,
               int M, int N, int Kp, int ldc, int Nz)
{
    __shared__ __align__(16) __bf16 As[128*32];
    __shared__ __align__(16) __bf16 Bs[128*32];
    const int tid = threadIdx.x;
    const int nbx = gridDim.x;
    const int lin = blockIdx.y * nbx + blockIdx.x;
    const int per = (nbx * gridDim.y) >> 3;
    const int logical = (lin & 7) * per + (lin >> 3);
    const int row0 = (logical / nbx) * 128, col0 = (logical % nbx) * 128;
    const int lane = tid & 63, wid = tid >> 6;
    const int wm = wid & 3, wn = wid >> 2;
    const int l15 = lane & 15, lk = lane >> 4;
    const int sr  = tid >> 2;
    const int sc8 = (tid & 3) * 8;

    f32x4 acc[2][4];
#pragma unroll
    for (int i = 0; i < 2; i++)
#pragma unroll
        for (int j = 0; j < 4; j++) acc[i][j] = (f32x4){0.f,0.f,0.f,0.f};

    for (int k0 = 0; k0 < Kp; k0 += 32) {
        __syncthreads();
        load_lds16(A  + (size_t)(row0+sr)*Kp + k0 + sc8, &As[wid*512]);
        load_lds16(Bt + (size_t)(col0+sr)*Kp + k0 + sc8, &Bs[wid*512]);
        __syncthreads();
        bf16x8 af[2], bfr[4];
#pragma unroll
        for (int i = 0; i < 2; i++)
            af[i]  = *(const bf16x8*)&As[(wm*32 + i*16 + l15)*32 + lk*8];
#pragma unroll
        for (int j = 0; j < 4; j++)
            bfr[j] = *(const bf16x8*)&Bs[(wn*64 + j*16 + l15)*32 + lk*8];
#pragma unroll
        for (int i = 0; i < 2; i++)
#pragma unroll
            for (int j = 0; j < 4; j++)
                acc[i][j] = __builtin_amdgcn_mfma_f32_16x16x32_bf16(af[i], bfr[j], acc[i][j], 0, 0, 0);
    }

#pragma unroll
    for (int i = 0; i < 2; i++) {
        int rbase = row0 + wm*32 + i*16 + lk*4;
#pragma unroll
        for (int j = 0; j < 4; j++) {
            int cc = col0 + wn*64 + j*16 + l15;
            if (cc >= Nz) continue;
            bool real = cc < N;
            float bv = (BIAS && real) ? bias[cc] : 0.f;
#pragma unroll
            for (int r = 0; r < 4; r++) {
                float v = real ? (acc[i][j][r] + bv) : 0.f;
                if (RELU) v = v > 0.f ? v : 0.f;
                if (BF16OUT) ((__bf16*)Cv)[(size_t)(rbase + r)*ldc + cc] = (__bf16)v;
                else         ((float*) Cv)[(size_t)(rbase + r)*ldc + cc] = v;
            }
        }
    }
}

// ---------------------------------------------------------------------------
// Split-K MFMA GEMM: partial[s][M][ldp] f32.  (reg-staged; small grids)
// ---------------------------------------------------------------------------
#define BKP 40
__global__ __launch_bounds__(256)
void gemm_mfma_splitk(const __bf16* __restrict__ A, const __bf16* __restrict__ Bt,
                      float* __restrict__ part, int M, int Kp, int ldp, int ksteps)
{
    __shared__ __align__(16) __bf16 As[128*BKP];
    __shared__ __align__(16) __bf16 Bs[128*BKP];
    const int tid = threadIdx.x;
    const int row0 = blockIdx.y*128, col0 = blockIdx.x*128;
    const int s = blockIdx.z;
    const int lane = tid & 63, wid = tid >> 6;
    const int wm = wid & 1, wn = wid >> 1;
    const int l15 = lane & 15, lk = lane >> 4;

    const int T = Kp >> 5;
    int kb = s*ksteps, ke = kb + ksteps;
    if (ke > T) ke = T;

    f32x4 acc[4][4];
#pragma unroll
    for (int i = 0; i < 4; i++)
#pragma unroll
        for (int j = 0; j < 4; j++) acc[i][j] = (f32x4){0.f,0.f,0.f,0.f};

    for (int kk = kb; kk < ke; kk++) {
        int k0 = kk*32;
        __syncthreads();
#pragma unroll
        for (int it = 0; it < 2; ++it) {
            int c = tid + it*256;
            int r = c >> 2, c16 = c & 3;
            uint4 va = *(const uint4*)(A  + (size_t)(row0+r)*Kp + k0 + c16*8);
            *(uint4*)&As[r*BKP + c16*8] = va;
            uint4 vb = *(const uint4*)(Bt + (size_t)(col0+r)*Kp + k0 + c16*8);
            *(uint4*)&Bs[r*BKP + c16*8] = vb;
        }
        __syncthreads();
        bf16x8 af[4], bfr[4];
#pragma unroll
        for (int i = 0; i < 4; i++) {
            af[i]  = *(const bf16x8*)&As[(wm*64 + i*16 + l15)*BKP + lk*8];
            bfr[i] = *(const bf16x8*)&Bs[(wn*64 + i*16 + l15)*BKP + lk*8];
        }
#pragma unroll
        for (int i = 0; i < 4; i++)
#pragma unroll
            for (int j = 0; j < 4; j++)
                acc[i][j] = __builtin_amdgcn_mfma_f32_16x16x32_bf16(af[i], bfr[j], acc[i][j], 0, 0, 0);
    }

#pragma unroll
    for (int i = 0; i < 4; i++) {
        int rbase = row0 + wm*64 + i*16 + lk*4;
#pragma unroll
        for (int j = 0; j < 4; j++) {
            int cc = col0 + wn*64 + j*16 + l15;
#pragma unroll
            for (int r = 0; r < 4; r++)
                part[((size_t)s*M + rbase + r)*ldp + cc] = acc[i][j][r];
        }
    }
}

// reduce S partials + bias (+relu) -> bf16 C (cols [N,Nz) zeroed)
template<bool RELU>
__global__ __launch_bounds__(256)
void reduce_splitk(const float* __restrict__ part, const float* __restrict__ bias,
                   __bf16* __restrict__ C, int M, int N, int ldp, int S,
                   int ldc, int Nz)
{
    int idx = blockIdx.x*256 + threadIdx.x;
    int nc4 = Nz >> 2;
    if (idx >= M*nc4) return;
    int r = idx / nc4, c = (idx - r*nc4)*4;
    float4 a = {0.f,0.f,0.f,0.f};
    for (int s = 0; s < S; s++) {
        float4 v = *(const float4*)(part + ((size_t)s*M + r)*ldp + c);
        a.x += v.x; a.y += v.y; a.z += v.z; a.w += v.w;
    }
    float vv[4] = {a.x, a.y, a.z, a.w};
    __bf16 o4[4];
#pragma unroll
    for (int j = 0; j < 4; j++) {
        float v = 0.f;
        if (c + j < N) {
            v = vv[j] + bias[c+j];
            if (RELU) v = v > 0.f ? v : 0.f;
        }
        o4[j] = (__bf16)v;
    }
    *(uint2*)&C[(size_t)r*ldc + c] = *(uint2*)o4;
}

// ---------------------------------------------------------------------------
// a_src[n,h], a_dst[n,h] from bf16 xh (stride 800)
// ---------------------------------------------------------------------------
__global__ __launch_bounds__(256)
void attn_logits(const __bf16* __restrict__ xh, const float* __restrict__ att_s,
                 const float* __restrict__ att_d,
                 float* __restrict__ a_src, float* __restrict__ a_dst)
{
    int idx = blockIdx.x*256 + threadIdx.x;
    if (idx >= NN*NH) return;
    int n = idx / NH, h = idx % NH;
    const __bf16* xr = xh + (size_t)n*800 + h*FX;
    const float* as = att_s + h*FX;
    const float* ad = att_d + h*FX;
    float s1 = 0.f, s2 = 0.f;
    for (int c = 0; c < FX; c++) {
        float v = (float)xr[c];
        s1 = fmaf(v, as[c], s1);
        s2 = fmaf(v, ad[c], s2);
    }
    a_src[idx] = s1;
    a_dst[idx] = s2;
}

// ---------------------------------------------------------------------------
// CSR build
// ---------------------------------------------------------------------------
__global__ void edge_count(const int* __restrict__ ei, int* __restrict__ deg)
{
    int e = blockIdx.x*256 + threadIdx.x;
    if (e >= NT) return;
    int dst = (e < NE) ? ei[NE + e] : (e - NE);
    atomicAdd(&deg[dst], 1);
}

__global__ __launch_bounds__(1024)
void scan_kernel(const int* __restrict__ deg, int* __restrict__ offs,
                 int* __restrict__ cursor, float* __restrict__ dinv)
{
    __shared__ int part[1024];
    int tid = threadIdx.x;
    int base = tid*16;
    int v[16]; int ssum = 0;
#pragma unroll
    for (int j = 0; j < 16; j++) {
        v[j] = deg[base+j];
        dinv[base+j] = rsqrtf((float)(v[j] > 0 ? v[j] : 1));
        ssum += v[j];
    }
    part[tid] = ssum;
    __syncthreads();
    for (int d = 1; d < 1024; d <<= 1) {
        int t = (tid >= d) ? part[tid-d] : 0;
        __syncthreads();
        part[tid] += t;
        __syncthreads();
    }
    int run = (tid == 0) ? 0 : part[tid-1];
#pragma unroll
    for (int j = 0; j < 16; j++) { offs[base+j] = run; cursor[base+j] = run; run += v[j]; }
    if (tid == 1023) offs[NN] = run;
}

__global__ void edge_scatter(const int* __restrict__ ei, int* __restrict__ cursor,
                             int* __restrict__ csr)
{
    int e = blockIdx.x*256 + threadIdx.x;
    if (e >= NT) return;
    int src, dst;
    if (e < NE) { src = ei[e]; dst = ei[NE + e]; }
    else        { src = e - NE; dst = e - NE; }
    int pos = atomicAdd(&cursor[dst], 1);
    csr[pos] = src;
}

// ---------------------------------------------------------------------------
// GAT aggregation: bf16 xh gather -> bf16 h (stride 800, cols 780..799 zero)
// ---------------------------------------------------------------------------
__global__ __launch_bounds__(256)
void gat_agg(const __bf16* __restrict__ xh, const float* __restrict__ a_src,
             const float* __restrict__ a_dst, const float* __restrict__ gat_b,
             const int* __restrict__ offs, const int* __restrict__ csr,
             __bf16* __restrict__ hbf)
{
    int n = blockIdx.x*4 + (threadIdx.x >> 6);
    if (n >= NN) return;
    int lane = threadIdx.x & 63;
    bool act = lane < 60;
    int h   = act ? (lane / 6) : 0;
    int sub = act ? (lane % 6) : 0;
    int cbase = h*FX + sub*13;
    int off = offs[n], end = offs[n+1];
    float adn = a_dst[n*NH + h];

    float m = -3.0e38f;
    for (int i = off; i < end; i++) {
        int s = csr[i];
        float ev = a_src[s*NH + h] + adn;
        ev = ev > 0.f ? ev : 0.2f*ev;
        m = fmaxf(m, ev);
    }
    float den = 0.f;
    float acc[13];
#pragma unroll
    for (int j = 0; j < 13; j++) acc[j] = 0.f;
    for (int i = off; i < end; i++) {
        int s = csr[i];
        float ev = a_src[s*NH + h] + adn;
        ev = ev > 0.f ? ev : 0.2f*ev;
        float ee = __expf(ev - m);
        den += ee;
        const __bf16* xr = xh + (size_t)s*800 + cbase;
#pragma unroll
        for (int j = 0; j < 13; j++) acc[j] = fmaf((float)xr[j], ee, acc[j]);
    }
    if (act) {
        float inv = 1.f / den;
        const float* bb = gat_b + cbase;
        __bf16* op = hbf + (size_t)n*800 + cbase;
#pragma unroll
        for (int j = 0; j < 13; j++) {
            float v = fmaf(acc[j], inv, bb[j]);
            op[j] = (__bf16)(v > 0.f ? v : 0.f);
        }
    } else {
        __bf16* op = hbf + (size_t)n*800 + 780 + (lane - 60)*5;
#pragma unroll
        for (int j = 0; j < 5; j++) op[j] = (__bf16)0.f;
    }
}

// ---------------------------------------------------------------------------
// GCN aggregation: bf16 hw gather -> bf16 g (stride 780)
// ---------------------------------------------------------------------------
__global__ __launch_bounds__(256)
void gcn_agg(const __bf16* __restrict__ hw, const float* __restrict__ dinv,
             const float* __restrict__ gcn_b, const int* __restrict__ offs,
             const int* __restrict__ csr, __bf16* __restrict__ g)
{
    int n = blockIdx.x*4 + (threadIdx.x >> 6);
    if (n >= NN) return;
    int lane = threadIdx.x & 63;
    int off = offs[n], end = offs[n+1];
    float dn = dinv[n];
    float acc[13];
#pragma unroll
    for (int j = 0; j < 13; j++) acc[j] = 0.f;
    for (int i = off; i < end; i++) {
        int s = csr[i];
        float w = dinv[s] * dn;
        const __bf16* r = hw + (size_t)s*800;
#pragma unroll
        for (int j = 0; j < 13; j++) {
            int c = lane + 64*j;
            if (c < HD) acc[j] = fmaf((float)r[c], w, acc[j]);
        }
    }
    __bf16* op = g + (size_t)n*HD;
#pragma unroll
    for (int j = 0; j < 13; j++) {
        int c = lane + 64*j;
        if (c < HD) {
            float v = acc[j] + gcn_b[c];
            op[c] = (__bf16)(v > 0.f ? v : 0.f);
        }
    }
}

// pool (bf16 g) -> bf16 d[b][1568]: [0:780)=max, [780:1560)=mean, pad 0
__global__ __launch_bounds__(256)
void pool_kernel(const __bf16* __restrict__ g, const int* __restrict__ goffs,
                 __bf16* __restrict__ d)
{
    int b = blockIdx.x;
    int tid = threadIdx.x;
    int s = goffs[b], e = goffs[b+1];
    float mx[4], sm[4];
#pragma unroll
    for (int j = 0; j < 4; j++) { mx[j] = -3.0e38f; sm[j] = 0.f; }
    for (int n = s; n < e; n++) {
        const __bf16* r = g + (size_t)n*HD;
#pragma unroll
        for (int j = 0; j < 4; j++) {
            int c = tid + 256*j;
            if (c < HD) { float v = (float)r[c]; mx[j] = fmaxf(mx[j], v); sm[j] += v; }
        }
    }
    int cnt = e - s;
    float inv = 1.f / (float)(cnt > 0 ? cnt : 1);
#pragma unroll
    for (int j = 0; j < 4; j++) {
        int c = tid + 256*j;
        if (c < HD) {
            d[(size_t)b*1568 + c]      = (__bf16)mx[j];
            d[(size_t)b*1568 + HD + c] = (__bf16)(sm[j] * inv);
        }
    }
    if (tid < 8) d[(size_t)b*1568 + 1560 + tid] = (__bf16)0.f;
}

// ---------------------------------------------------------------------------
// Protein conv v4: 64-k phases (16 total), staging stride 76 (bank spread),
// 28 MFMA/wave/phase window over the staged-gather latency.
// ---------------------------------------------------------------------------
#define CP 104            // P lds col stride (cols 0..99 used)
#define SSTR 76           // staging k stride (64 data + 12 pad)
#define SB2 (112*SSTR)    // elems per staging buffer (8512)

__global__ __launch_bounds__(512)
void conv_gemm2(const int* __restrict__ target, const __bf16* __restrict__ embbf,
                const __bf16* __restrict__ w2, const float* __restrict__ conv_b,
                __bf16* __restrict__ cbuf)
{
    __shared__ __align__(16) __bf16 Pl[256*CP];   // 53.2 KB total
    __bf16* Bs = Pl;                              // staging: [0, 2*SB2)
    int* tg = (int*)&Pl[2*SB2];                   // 1024 ints after staging
    const int b = blockIdx.x;
    const int tid = threadIdx.x;
    const int w = tid >> 6, lane = tid & 63;
    const int l15 = lane & 15, lk = lane >> 4;

    for (int i = tid; i < 1024; i += 512)
        tg[i] = ((i < SEQ) ? target[b*SEQ + i] : 8000) * 112;
    __syncthreads();

    const bool st = tid < 448;
    const int r = tid & 63;          // k-row within 64-tile
    const int c = (tid >> 6) & 7;    // col chunk 0..6 (16 cols each)

    uint4 sv0, sv1;
    auto stage_load = [&](int p) {
        if (!st) return;
        const ushort* eb = (const ushort*)embbf + tg[p*64 + r] + c*16;
        sv0 = *(const uint4*)(eb);
        sv1 = *(const uint4*)(eb + 8);
    };
    auto stage_write = [&](int buf) {
        if (!st) return;
        const __bf16* s8a = (const __bf16*)&sv0;
        const __bf16* s8b = (const __bf16*)&sv1;
        __bf16* base = &Bs[buf*SB2 + (c*16)*SSTR + r];
#pragma unroll
        for (int j = 0; j < 8; j++) base[j*SSTR] = s8a[j];
#pragma unroll
        for (int j = 0; j < 8; j++) base[(8+j)*SSTR] = s8b[j];
    };

    f32x4 acc[7][2];
#pragma unroll
    for (int i = 0; i < 7; i++) {
        acc[i][0] = (f32x4){0.f,0.f,0.f,0.f};
        acc[i][1] = (f32x4){0.f,0.f,0.f,0.f};
    }

    const __bf16* w2w0 = w2 + (size_t)(w*32 + l15)*1024 + lk*8;
    const __bf16* w2w1 = w2w0 + (size_t)16*1024;

    stage_load(0);
    stage_write(0);
    int cur = 0;
    for (int p = 0; p < 16; ++p) {
        __syncthreads();
        if (p+1 < 16) stage_load(p+1);
        const __bf16* bsc = Bs + cur*SB2 + lk*8;
        __builtin_amdgcn_s_setprio(1);
#pragma unroll
        for (int k32 = 0; k32 < 2; k32++) {
            bf16x8 bf0 = *(const bf16x8*)(w2w0 + p*64 + k32*32);
            bf16x8 bf1 = *(const bf16x8*)(w2w1 + p*64 + k32*32);
#pragma unroll
            for (int mt = 0; mt < 7; mt++) {
                bf16x8 af = *(const bf16x8*)(bsc + (mt*16 + l15)*SSTR + k32*32);
                acc[mt][0] = __builtin_amdgcn_mfma_f32_16x16x32_bf16(af, bf0, acc[mt][0], 0, 0, 0);
                acc[mt][1] = __builtin_amdgcn_mfma_f32_16x16x32_bf16(af, bf1, acc[mt][1], 0, 0, 0);
            }
        }
        __builtin_amdgcn_s_setprio(0);
        if (p+1 < 16) stage_write(cur^1);
        cur ^= 1;
    }

    __syncthreads();   // staging + tg dead; write P over it
#pragma unroll
    for (int mt = 0; mt < 7; mt++) {
#pragma unroll
        for (int nt = 0; nt < 2; nt++) {
            int op = w*32 + nt*16 + l15;
            int c0 = mt*16 + lk*4;
            if (c0 >= 100) continue;   // cols >= 100 never read
            __bf16 o4[4];
#pragma unroll
            for (int rr = 0; rr < 4; rr++) o4[rr] = (__bf16)acc[mt][nt][rr];
            *(uint2*)&Pl[op*CP + c0] = *(uint2*)o4;
        }
    }
    __syncthreads();

    // shift-add: thread (o = tid&31, tg16 = tid>>5): 6 t's each
    {
        int o = tid & 31, tg16 = tid >> 5;
        float cb = conv_b[o];
#pragma unroll
        for (int j = 0; j < 6; j++) {
            int t = tg16*6 + j;
            if (t >= CLEN) continue;
            float s = cb;
#pragma unroll
            for (int k = 0; k < 8; k++)
                s += (float)Pl[(k*32 + o)*CP + t + k];
            cbuf[(size_t)b*2976 + o*CLEN + t] = (__bf16)s;
        }
    }
}

// ---------------------------------------------------------------------------
// mlp3: out[r] = dot(o2bf[r,0:512], w) + b   (wave per row)
// ---------------------------------------------------------------------------
__global__ __launch_bounds__(256)
void mlp3_dot(const __bf16* __restrict__ o2, const float* __restrict__ w,
              const float* __restrict__ bias, float* __restrict__ out)
{
    int row = blockIdx.x*4 + (threadIdx.x >> 6);
    int lane = threadIdx.x & 63;
    bf16x8 v = *(const bf16x8*)(o2 + (size_t)row*512 + lane*8);
    float4 w0 = *(const float4*)(w + lane*8);
    float4 w1 = *(const float4*)(w + lane*8 + 4);
    float s = (float)v[0]*w0.x + (float)v[1]*w0.y + (float)v[2]*w0.z + (float)v[3]*w0.w
            + (float)v[4]*w1.x + (float)v[5]*w1.y + (float)v[6]*w1.z + (float)v[7]*w1.w;
#pragma unroll
    for (int off = 32; off > 0; off >>= 1) s += __shfl_down(s, off);
    if (lane == 0) out[row] = s + bias[0];
}

// ---------------------------------------------------------------------------
extern "C" void kernel_launch(void* const* d_in, const int* in_sizes, int n_in,
                              void* d_out, int out_size, void* d_ws, size_t ws_size,
                              hipStream_t stream)
{
    const float* x      = (const float*)d_in[0];
    const int*   ei     = (const int*)  d_in[1];
    const int*   batch  = (const int*)  d_in[2];
    const int*   target = (const int*)  d_in[3];
    const float* gat_w  = (const float*)d_in[4];
    const float* att_s  = (const float*)d_in[5];
    const float* att_d  = (const float*)d_in[6];
    const float* gat_b  = (const float*)d_in[7];
    const float* gcn_w  = (const float*)d_in[8];
    const float* gcn_b  = (const float*)d_in[9];
    const float* fcg1_w = (const float*)d_in[10];
    const float* fcg1_b = (const float*)d_in[11];
    const float* fcg2_w = (const float*)d_in[12];
    const float* fcg2_b = (const float*)d_in[13];
    const float* emb_w  = (const float*)d_in[14];
    const float* conv_w = (const float*)d_in[15];
    const float* conv_b = (const float*)d_in[16];
    const float* fcxt_w = (const float*)d_in[17];
    const float* fcxt_b = (const float*)d_in[18];
    const float* mlp1_w = (const float*)d_in[19];
    const float* mlp1_b = (const float*)d_in[20];
    const float* mlp2_w = (const float*)d_in[21];
    const float* mlp2_b = (const float*)d_in[22];
    const float* mlp3_w = (const float*)d_in[23];
    const float* mlp3_b = (const float*)d_in[24];
    float* out = (float*)d_out;

    char* ws = (char*)d_ws;
    size_t off = 0;
    auto alloc = [&](size_t bytes) -> char* {
        char* p = ws + off;
        off = (off + bytes + 255) & ~(size_t)255;
        return p;
    };
    __bf16* xhbf  = (__bf16*)alloc((size_t)NN*800*2);  // xh bf16, reused as hw bf16
    __bf16* g     = (__bf16*)alloc((size_t)NN*HD*2);
    char*  hbf_rg = alloc((size_t)NN*800*2);           // Abf -> hbf -> splitk partial
    __bf16* Abf   = (__bf16*)hbf_rg;
    __bf16* hbf   = (__bf16*)hbf_rg;
    float* partial= (float*)hbf_rg;                    // after hbf dead
    __bf16* wgat  = (__bf16*)alloc((size_t)896*96*2);
    __bf16* wgcn  = (__bf16*)alloc((size_t)896*800*2);
    __bf16* wg1   = (__bf16*)alloc((size_t)1536*1568*2);
    __bf16* wg2   = (__bf16*)alloc((size_t)128*1504*2);
    __bf16* wxt   = (__bf16*)alloc((size_t)128*2976*2);
    __bf16* wm1   = (__bf16*)alloc((size_t)1024*256*2);
    __bf16* wm2   = (__bf16*)alloc((size_t)512*1024*2);
    __bf16* convw2= (__bf16*)alloc((size_t)256*1024*2);
    __bf16* embbf = (__bf16*)alloc((size_t)8001*112*2);
    float* a_src  = (float*)alloc((size_t)NN*NH*4);
    float* a_dst  = (float*)alloc((size_t)NN*NH*4);
    int*   deg    = (int*)alloc((size_t)NN*4);
    int*   offs   = (int*)alloc((size_t)(NN+1)*4);
    int*   cursor = (int*)alloc((size_t)NN*4);
    int*   csr    = (int*)alloc((size_t)NT*4);
    float* dinv   = (float*)alloc((size_t)NN*4);
    int*   goffs  = (int*)alloc((size_t)(NG+1)*4);
    __bf16* dpool = (__bf16*)alloc((size_t)NG*1568*2);
    __bf16* d1bf  = (__bf16*)alloc((size_t)NG*1504*2);
    __bf16* cbuf  = (__bf16*)alloc((size_t)NG*NF*CLEN*2);
    __bf16* obuf  = (__bf16*)alloc((size_t)NG*256*2);
    __bf16* o1bf  = (__bf16*)alloc((size_t)NG*1024*2);
    __bf16* o2bf  = (__bf16*)alloc((size_t)NG*512*2);

    __bf16* hwbf = xhbf;   // xh dead after gat_agg

    hipMemsetAsync(deg, 0, (size_t)NN*4, stream);

    // --- input-only transforms ---
    preproc_all<<<dim3((unsigned)PRE_BLOCKS), 256, 0, stream>>>(
        emb_w, embbf, conv_w, convw2, x, Abf, batch, goffs);
    transpose_w<<<dim3(TRANS_BLOCKS), 256, 0, stream>>>(
        fcg1_w, wg1, gcn_w, wgcn, gat_w, wgat, fcg2_w, wg2,
        fcxt_w, wxt, mlp1_w, wm1, mlp2_w, wm2);

    // --- protein conv (independent of graph branch; run early) ---
    conv_gemm2<<<dim3(NG), 512, 0, stream>>>(target, embbf, convw2, conv_b, cbuf);

    // --- GAT linear: xh = x @ gat_w (Kp=96), bf16 out stride 800 ---
    gemm_mfma<false,false,true>
        <<<dim3(7, NN/128), 512, 0, stream>>>(Abf, wgat, nullptr, xhbf, NN, HD, 96, 800, 800);
    attn_logits<<<dim3((NN*NH+255)/256), 256, 0, stream>>>(xhbf, att_s, att_d, a_src, a_dst);

    // --- CSR (dinv folded into scan) ---
    edge_count  <<<dim3(NT/256), 256, 0, stream>>>(ei, deg);
    scan_kernel <<<1, 1024, 0, stream>>>(deg, offs, cursor, dinv);
    edge_scatter<<<dim3(NT/256), 256, 0, stream>>>(ei, cursor, csr);

    // --- GAT aggregate -> hbf (overwrites Abf; Abf dead) ---
    gat_agg<<<dim3(NN/4), 256, 0, stream>>>(xhbf, a_src, a_dst, gat_b, offs, csr, hbf);

    // --- GCN linear (bf16 out) + aggregate (bf16 g) ---
    gemm_mfma<false,false,true>
        <<<dim3(7, NN/128), 512, 0, stream>>>(hbf, wgcn, nullptr, hwbf, NN, HD, 800, 800, 800);
    gcn_agg<<<dim3(NN/4), 256, 0, stream>>>(hwbf, dinv, gcn_b, offs, csr, g);

    // --- pooling (goffs from preproc) ---
    pool_kernel<<<NG, 256, 0, stream>>>(g, goffs, dpool);

    // --- FC stack via split-K (partial aliases hbf; dead after gcn gemm) ---
    gemm_mfma_splitk<<<dim3(12, 4, 4), 256, 0, stream>>>(dpool, wg1, partial, NG, 1568, 1536, 13);
    reduce_splitk<true><<<dim3((NG*(1504/4)+255)/256), 256, 0, stream>>>(partial, fcg1_b, d1bf, NG, 1500, 1536, 4, 1504, 1504);
    gemm_mfma_splitk<<<dim3(1, 4, 12), 256, 0, stream>>>(d1bf, wg2, partial, NG, 1504, 128, 4);
    reduce_splitk<false><<<dim3((NG*32+255)/256), 256, 0, stream>>>(partial, fcg2_b, obuf, NG, 128, 128, 12, 256, 128);
    gemm_mfma_splitk<<<dim3(1, 4, 24), 256, 0, stream>>>(cbuf, wxt, partial, NG, 2976, 128, 4);
    reduce_splitk<false><<<dim3((NG*32+255)/256), 256, 0, stream>>>(partial, fcxt_b, obuf + 128, NG, 128, 128, 24, 256, 128);
    gemm_mfma_splitk<<<dim3(8, 4, 2), 256, 0, stream>>>(obuf, wm1, partial, NG, 256, 1024, 4);
    reduce_splitk<true><<<dim3((NG*256+255)/256), 256, 0, stream>>>(partial, mlp1_b, o1bf, NG, 1024, 1024, 2, 1024, 1024);
    gemm_mfma_splitk<<<dim3(4, 4, 8), 256, 0, stream>>>(o1bf, wm2, partial, NG, 1024, 512, 4);
    reduce_splitk<true><<<dim3((NG*128+255)/256), 256, 0, stream>>>(partial, mlp2_b, o2bf, NG, 512, 512, 8, 512, 512);

    mlp3_dot<<<dim3(NG/4), 256, 0, stream>>>(o2bf, mlp3_w, mlp3_b, out);
}

// Round 13
// 352.563 us; speedup vs baseline: 1.1805x; 1.1805x over previous
//
#include <hip/hip_runtime.h>

#define NN 16384      // nodes
#define NE 65536      // edges
#define NT 81920      // edges + self loops
#define NG 512        // graphs
#define NH 10         // heads
#define FX 78         // features per head
#define HD 780        // hidden = NH*FX
#define SEQ 1000
#define EMB 100
#define NF 32
#define KS 8
#define CLEN 93

typedef __bf16 bf16x8 __attribute__((ext_vector_type(8)));
typedef float  f32x4  __attribute__((ext_vector_type(4)));

__device__ inline void load_lds16(const void* g, void* l)
{
    __builtin_amdgcn_global_load_lds(
        (const __attribute__((address_space(1))) void*)g,
        (__attribute__((address_space(3))) void*)l, 16, 0, 0);
}

// ---------------------------------------------------------------------------
// preproc: emb cast, conv W' repack, x cast, goffs (all coalesced-friendly)
// ---------------------------------------------------------------------------
__global__ __launch_bounds__(256)
void preproc_all(const float* __restrict__ emb_w, __bf16* __restrict__ embbf,
                 const float* __restrict__ conv_w, __bf16* __restrict__ w2,
                 const float* __restrict__ x, __bf16* __restrict__ Abf,
                 const int* __restrict__ batch, int* __restrict__ goffs)
{
    long idx = (long)blockIdx.x*256 + threadIdx.x;
    if (idx < 896112L) {
        int r = idx / 112, c = idx - (long)(idx/112)*112;
        embbf[idx] = (__bf16)((r < 8000 && c < EMB) ? emb_w[(size_t)r*EMB + c] : 0.f);
        return;
    }
    idx -= 896112L;
    if (idx < 262144L) {
        int op = idx >> 10, i = idx & 1023;
        int o = op & 31, k = op >> 5;
        w2[idx] = (i < SEQ) ? (__bf16)conv_w[((size_t)o*SEQ + i)*KS + k] : (__bf16)0.f;
        return;
    }
    idx -= 262144L;
    if (idx < 1572864L) {
        int r = idx / 96, c = idx - (long)(idx/96)*96;
        Abf[idx] = (c < FX) ? (__bf16)x[(size_t)r*FX + c] : (__bf16)0.f;
        return;
    }
    idx -= 1572864L;
    if (idx <= NG) {
        int b = (int)idx;
        if (b == NG) { goffs[NG] = NN; return; }
        int lo = 0, hi = NN;
        while (lo < hi) { int mid = (lo+hi) >> 1; if (batch[mid] < b) lo = mid+1; else hi = mid; }
        goffs[b] = lo;
    }
}
#define PRE_TOTAL 2731633L
#define PRE_BLOCKS ((PRE_TOTAL + 255) / 256)

// ---------------------------------------------------------------------------
// LDS-tiled transpose+cast for all FC/GNN weights: out[n][k] = (bf16)B[k][n],
// zero-padded to [Np][Kp]. One block = one 32x32 tile; both sides coalesced.
// ---------------------------------------------------------------------------
__global__ __launch_bounds__(256)
void transpose_w(const float* __restrict__ fcg1_w, __bf16* __restrict__ wg1,
                 const float* __restrict__ gcn_w,  __bf16* __restrict__ wgcn,
                 const float* __restrict__ gat_w,  __bf16* __restrict__ wgat,
                 const float* __restrict__ fcg2_w, __bf16* __restrict__ wg2,
                 const float* __restrict__ fcxt_w, __bf16* __restrict__ wxt,
                 const float* __restrict__ mlp1_w, __bf16* __restrict__ wm1,
                 const float* __restrict__ mlp2_w, __bf16* __restrict__ wm2)
{
    __shared__ float tile[32][33];
    int t = blockIdx.x;
    const float* B; __bf16* out; int K, N, Kp, tk_n;
    if (t < 2352)              { B=fcg1_w; out=wg1;  K=1560; N=1500; Kp=1568; tk_n=49; }
    else if ((t -= 2352) < 700){ B=gcn_w;  out=wgcn; K=780;  N=780;  Kp=800;  tk_n=25; }
    else if ((t -= 700) < 84)  { B=gat_w;  out=wgat; K=78;   N=780;  Kp=96;   tk_n=3;  }
    else if ((t -= 84) < 188)  { B=fcg2_w; out=wg2;  K=1500; N=128;  Kp=1504; tk_n=47; }
    else if ((t -= 188) < 372) { B=fcxt_w; out=wxt;  K=2976; N=128;  Kp=2976; tk_n=93; }
    else if ((t -= 372) < 256) { B=mlp1_w; out=wm1;  K=256;  N=1024; Kp=256;  tk_n=8;  }
    else { t -= 256;             B=mlp2_w; out=wm2;  K=1024; N=512;  Kp=1024; tk_n=32; }
    int k0 = (t % tk_n) * 32, n0 = (t / tk_n) * 32;
    int jj = threadIdx.x & 31, ii0 = threadIdx.x >> 5;
#pragma unroll
    for (int g = 0; g < 4; g++) {
        int i = ii0 + g*8;
        int gk = k0 + i, gn = n0 + jj;
        tile[i][jj] = (gk < K && gn < N) ? B[(size_t)gk*N + gn] : 0.f;
    }
    __syncthreads();
#pragma unroll
    for (int g = 0; g < 4; g++) {
        int i = ii0 + g*8;
        out[(size_t)(n0 + i)*Kp + k0 + jj] = (__bf16)tile[jj][i];
    }
}
#define TRANS_BLOCKS 4464

// ---------------------------------------------------------------------------
// bf16 MFMA GEMM (full-K): 8 waves, 128x128 tile, wave = 32x64 subtile.
// global_load_lds(16B) staging, linear [128][32] LDS, XCD bijective swizzle.
// ---------------------------------------------------------------------------
template<bool BIAS, bool RELU, bool BF16OUT>
__global__ __launch_bounds__(512)
void gemm_mfma(const __bf16* __restrict__ A, const __bf16* __restrict__ Bt,
               const float* __restrict__ bias, void* __restrict__ Cv,
               int M, int N, int Kp, int ldc, int Nz)
{
    __shared__ __align__(16) __bf16 As[128*32];
    __shared__ __align__(16) __bf16 Bs[128*32];
    const int tid = threadIdx.x;
    const int nbx = gridDim.x;
    const int lin = blockIdx.y * nbx + blockIdx.x;
    const int per = (nbx * gridDim.y) >> 3;
    const int logical = (lin & 7) * per + (lin >> 3);
    const int row0 = (logical / nbx) * 128, col0 = (logical % nbx) * 128;
    const int lane = tid & 63, wid = tid >> 6;
    const int wm = wid & 3, wn = wid >> 2;
    const int l15 = lane & 15, lk = lane >> 4;
    const int sr  = tid >> 2;
    const int sc8 = (tid & 3) * 8;

    f32x4 acc[2][4];
#pragma unroll
    for (int i = 0; i < 2; i++)
#pragma unroll
        for (int j = 0; j < 4; j++) acc[i][j] = (f32x4){0.f,0.f,0.f,0.f};

    for (int k0 = 0; k0 < Kp; k0 += 32) {
        __syncthreads();
        load_lds16(A  + (size_t)(row0+sr)*Kp + k0 + sc8, &As[wid*512]);
        load_lds16(Bt + (size_t)(col0+sr)*Kp + k0 + sc8, &Bs[wid*512]);
        __syncthreads();
        bf16x8 af[2], bfr[4];
#pragma unroll
        for (int i = 0; i < 2; i++)
            af[i]  = *(const bf16x8*)&As[(wm*32 + i*16 + l15)*32 + lk*8];
#pragma unroll
        for (int j = 0; j < 4; j++)
            bfr[j] = *(const bf16x8*)&Bs[(wn*64 + j*16 + l15)*32 + lk*8];
#pragma unroll
        for (int i = 0; i < 2; i++)
#pragma unroll
            for (int j = 0; j < 4; j++)
                acc[i][j] = __builtin_amdgcn_mfma_f32_16x16x32_bf16(af[i], bfr[j], acc[i][j], 0, 0, 0);
    }

#pragma unroll
    for (int i = 0; i < 2; i++) {
        int rbase = row0 + wm*32 + i*16 + lk*4;
#pragma unroll
        for (int j = 0; j < 4; j++) {
            int cc = col0 + wn*64 + j*16 + l15;
            if (cc >= Nz) continue;
            bool real = cc < N;
            float bv = (BIAS && real) ? bias[cc] : 0.f;
#pragma unroll
            for (int r = 0; r < 4; r++) {
                float v = real ? (acc[i][j][r] + bv) : 0.f;
                if (RELU) v = v > 0.f ? v : 0.f;
                if (BF16OUT) ((__bf16*)Cv)[(size_t)(rbase + r)*ldc + cc] = (__bf16)v;
                else         ((float*) Cv)[(size_t)(rbase + r)*ldc + cc] = v;
            }
        }
    }
}

// ---------------------------------------------------------------------------
// Split-K MFMA GEMM: partial[s][M][ldp] f32.  (reg-staged; small grids)
// ---------------------------------------------------------------------------
#define BKP 40
__global__ __launch_bounds__(256)
void gemm_mfma_splitk(const __bf16* __restrict__ A, const __bf16* __restrict__ Bt,
                      float* __restrict__ part, int M, int Kp, int ldp, int ksteps)
{
    __shared__ __align__(16) __bf16 As[128*BKP];
    __shared__ __align__(16) __bf16 Bs[128*BKP];
    const int tid = threadIdx.x;
    const int row0 = blockIdx.y*128, col0 = blockIdx.x*128;
    const int s = blockIdx.z;
    const int lane = tid & 63, wid = tid >> 6;
    const int wm = wid & 1, wn = wid >> 1;
    const int l15 = lane & 15, lk = lane >> 4;

    const int T = Kp >> 5;
    int kb = s*ksteps, ke = kb + ksteps;
    if (ke > T) ke = T;

    f32x4 acc[4][4];
#pragma unroll
    for (int i = 0; i < 4; i++)
#pragma unroll
        for (int j = 0; j < 4; j++) acc[i][j] = (f32x4){0.f,0.f,0.f,0.f};

    for (int kk = kb; kk < ke; kk++) {
        int k0 = kk*32;
        __syncthreads();
#pragma unroll
        for (int it = 0; it < 2; ++it) {
            int c = tid + it*256;
            int r = c >> 2, c16 = c & 3;
            uint4 va = *(const uint4*)(A  + (size_t)(row0+r)*Kp + k0 + c16*8);
            *(uint4*)&As[r*BKP + c16*8] = va;
            uint4 vb = *(const uint4*)(Bt + (size_t)(col0+r)*Kp + k0 + c16*8);
            *(uint4*)&Bs[r*BKP + c16*8] = vb;
        }
        __syncthreads();
        bf16x8 af[4], bfr[4];
#pragma unroll
        for (int i = 0; i < 4; i++) {
            af[i]  = *(const bf16x8*)&As[(wm*64 + i*16 + l15)*BKP + lk*8];
            bfr[i] = *(const bf16x8*)&Bs[(wn*64 + i*16 + l15)*BKP + lk*8];
        }
#pragma unroll
        for (int i = 0; i < 4; i++)
#pragma unroll
            for (int j = 0; j < 4; j++)
                acc[i][j] = __builtin_amdgcn_mfma_f32_16x16x32_bf16(af[i], bfr[j], acc[i][j], 0, 0, 0);
    }

#pragma unroll
    for (int i = 0; i < 4; i++) {
        int rbase = row0 + wm*64 + i*16 + lk*4;
#pragma unroll
        for (int j = 0; j < 4; j++) {
            int cc = col0 + wn*64 + j*16 + l15;
#pragma unroll
            for (int r = 0; r < 4; r++)
                part[((size_t)s*M + rbase + r)*ldp + cc] = acc[i][j][r];
        }
    }
}

// reduce S partials + bias (+relu) -> bf16 C (cols [N,Nz) zeroed)
template<bool RELU>
__global__ __launch_bounds__(256)
void reduce_splitk(const float* __restrict__ part, const float* __restrict__ bias,
                   __bf16* __restrict__ C, int M, int N, int ldp, int S,
                   int ldc, int Nz)
{
    int idx = blockIdx.x*256 + threadIdx.x;
    int nc4 = Nz >> 2;
    if (idx >= M*nc4) return;
    int r = idx / nc4, c = (idx - r*nc4)*4;
    float4 a = {0.f,0.f,0.f,0.f};
    for (int s = 0; s < S; s++) {
        float4 v = *(const float4*)(part + ((size_t)s*M + r)*ldp + c);
        a.x += v.x; a.y += v.y; a.z += v.z; a.w += v.w;
    }
    float vv[4] = {a.x, a.y, a.z, a.w};
    __bf16 o4[4];
#pragma unroll
    for (int j = 0; j < 4; j++) {
        float v = 0.f;
        if (c + j < N) {
            v = vv[j] + bias[c+j];
            if (RELU) v = v > 0.f ? v : 0.f;
        }
        o4[j] = (__bf16)v;
    }
    *(uint2*)&C[(size_t)r*ldc + c] = *(uint2*)o4;
}

// ---------------------------------------------------------------------------
// a_src[n,h], a_dst[n,h] from bf16 xh (stride 800)
// ---------------------------------------------------------------------------
__global__ __launch_bounds__(256)
void attn_logits(const __bf16* __restrict__ xh, const float* __restrict__ att_s,
                 const float* __restrict__ att_d,
                 float* __restrict__ a_src, float* __restrict__ a_dst)
{
    int idx = blockIdx.x*256 + threadIdx.x;
    if (idx >= NN*NH) return;
    int n = idx / NH, h = idx % NH;
    const __bf16* xr = xh + (size_t)n*800 + h*FX;
    const float* as = att_s + h*FX;
    const float* ad = att_d + h*FX;
    float s1 = 0.f, s2 = 0.f;
    for (int c = 0; c < FX; c++) {
        float v = (float)xr[c];
        s1 = fmaf(v, as[c], s1);
        s2 = fmaf(v, ad[c], s2);
    }
    a_src[idx] = s1;
    a_dst[idx] = s2;
}

// ---------------------------------------------------------------------------
// CSR build
// ---------------------------------------------------------------------------
__global__ void edge_count(const int* __restrict__ ei, int* __restrict__ deg)
{
    int e = blockIdx.x*256 + threadIdx.x;
    if (e >= NT) return;
    int dst = (e < NE) ? ei[NE + e] : (e - NE);
    atomicAdd(&deg[dst], 1);
}

__global__ __launch_bounds__(1024)
void scan_kernel(const int* __restrict__ deg, int* __restrict__ offs,
                 int* __restrict__ cursor, float* __restrict__ dinv)
{
    __shared__ int part[1024];
    int tid = threadIdx.x;
    int base = tid*16;
    int v[16]; int ssum = 0;
#pragma unroll
    for (int j = 0; j < 16; j++) {
        v[j] = deg[base+j];
        dinv[base+j] = rsqrtf((float)(v[j] > 0 ? v[j] : 1));
        ssum += v[j];
    }
    part[tid] = ssum;
    __syncthreads();
    for (int d = 1; d < 1024; d <<= 1) {
        int t = (tid >= d) ? part[tid-d] : 0;
        __syncthreads();
        part[tid] += t;
        __syncthreads();
    }
    int run = (tid == 0) ? 0 : part[tid-1];
#pragma unroll
    for (int j = 0; j < 16; j++) { offs[base+j] = run; cursor[base+j] = run; run += v[j]; }
    if (tid == 1023) offs[NN] = run;
}

__global__ void edge_scatter(const int* __restrict__ ei, int* __restrict__ cursor,
                             int* __restrict__ csr)
{
    int e = blockIdx.x*256 + threadIdx.x;
    if (e >= NT) return;
    int src, dst;
    if (e < NE) { src = ei[e]; dst = ei[NE + e]; }
    else        { src = e - NE; dst = e - NE; }
    int pos = atomicAdd(&cursor[dst], 1);
    csr[pos] = src;
}

// ---------------------------------------------------------------------------
// GAT aggregation: bf16 xh gather -> bf16 h (stride 800, cols 780..799 zero)
// ---------------------------------------------------------------------------
__global__ __launch_bounds__(256)
void gat_agg(const __bf16* __restrict__ xh, const float* __restrict__ a_src,
             const float* __restrict__ a_dst, const float* __restrict__ gat_b,
             const int* __restrict__ offs, const int* __restrict__ csr,
             __bf16* __restrict__ hbf)
{
    int n = blockIdx.x*4 + (threadIdx.x >> 6);
    if (n >= NN) return;
    int lane = threadIdx.x & 63;
    bool act = lane < 60;
    int h   = act ? (lane / 6) : 0;
    int sub = act ? (lane % 6) : 0;
    int cbase = h*FX + sub*13;
    int off = offs[n], end = offs[n+1];
    float adn = a_dst[n*NH + h];

    float m = -3.0e38f;
    for (int i = off; i < end; i++) {
        int s = csr[i];
        float ev = a_src[s*NH + h] + adn;
        ev = ev > 0.f ? ev : 0.2f*ev;
        m = fmaxf(m, ev);
    }
    float den = 0.f;
    float acc[13];
#pragma unroll
    for (int j = 0; j < 13; j++) acc[j] = 0.f;
    for (int i = off; i < end; i++) {
        int s = csr[i];
        float ev = a_src[s*NH + h] + adn;
        ev = ev > 0.f ? ev : 0.2f*ev;
        float ee = __expf(ev - m);
        den += ee;
        const __bf16* xr = xh + (size_t)s*800 + cbase;
#pragma unroll
        for (int j = 0; j < 13; j++) acc[j] = fmaf((float)xr[j], ee, acc[j]);
    }
    if (act) {
        float inv = 1.f / den;
        const float* bb = gat_b + cbase;
        __bf16* op = hbf + (size_t)n*800 + cbase;
#pragma unroll
        for (int j = 0; j < 13; j++) {
            float v = fmaf(acc[j], inv, bb[j]);
            op[j] = (__bf16)(v > 0.f ? v : 0.f);
        }
    } else {
        __bf16* op = hbf + (size_t)n*800 + 780 + (lane - 60)*5;
#pragma unroll
        for (int j = 0; j < 5; j++) op[j] = (__bf16)0.f;
    }
}

// ---------------------------------------------------------------------------
// GCN aggregation: bf16 hw gather -> bf16 g (stride 780)
// ---------------------------------------------------------------------------
__global__ __launch_bounds__(256)
void gcn_agg(const __bf16* __restrict__ hw, const float* __restrict__ dinv,
             const float* __restrict__ gcn_b, const int* __restrict__ offs,
             const int* __restrict__ csr, __bf16* __restrict__ g)
{
    int n = blockIdx.x*4 + (threadIdx.x >> 6);
    if (n >= NN) return;
    int lane = threadIdx.x & 63;
    int off = offs[n], end = offs[n+1];
    float dn = dinv[n];
    float acc[13];
#pragma unroll
    for (int j = 0; j < 13; j++) acc[j] = 0.f;
    for (int i = off; i < end; i++) {
        int s = csr[i];
        float w = dinv[s] * dn;
        const __bf16* r = hw + (size_t)s*800;
#pragma unroll
        for (int j = 0; j < 13; j++) {
            int c = lane + 64*j;
            if (c < HD) acc[j] = fmaf((float)r[c], w, acc[j]);
        }
    }
    __bf16* op = g + (size_t)n*HD;
#pragma unroll
    for (int j = 0; j < 13; j++) {
        int c = lane + 64*j;
        if (c < HD) {
            float v = acc[j] + gcn_b[c];
            op[c] = (__bf16)(v > 0.f ? v : 0.f);
        }
    }
}

// pool (bf16 g) -> bf16 d[b][1568]: [0:780)=max, [780:1560)=mean, pad 0
__global__ __launch_bounds__(256)
void pool_kernel(const __bf16* __restrict__ g, const int* __restrict__ goffs,
                 __bf16* __restrict__ d)
{
    int b = blockIdx.x;
    int tid = threadIdx.x;
    int s = goffs[b], e = goffs[b+1];
    float mx[4], sm[4];
#pragma unroll
    for (int j = 0; j < 4; j++) { mx[j] = -3.0e38f; sm[j] = 0.f; }
    for (int n = s; n < e; n++) {
        const __bf16* r = g + (size_t)n*HD;
#pragma unroll
        for (int j = 0; j < 4; j++) {
            int c = tid + 256*j;
            if (c < HD) { float v = (float)r[c]; mx[j] = fmaxf(mx[j], v); sm[j] += v; }
        }
    }
    int cnt = e - s;
    float inv = 1.f / (float)(cnt > 0 ? cnt : 1);
#pragma unroll
    for (int j = 0; j < 4; j++) {
        int c = tid + 256*j;
        if (c < HD) {
            d[(size_t)b*1568 + c]      = (__bf16)mx[j];
            d[(size_t)b*1568 + HD + c] = (__bf16)(sm[j] * inv);
        }
    }
    if (tid < 8) d[(size_t)b*1568 + 1560 + tid] = (__bf16)0.f;
}

// ---------------------------------------------------------------------------
// Protein conv (round-11 known-good): 32-k phases, stride-40 staging.
// ---------------------------------------------------------------------------
#define CP 104          // P lds col stride (cols 0..99 used)
#define SB (112*40)     // one staging buffer, elements

__global__ __launch_bounds__(512)
void conv_gemm2(const int* __restrict__ target, const __bf16* __restrict__ embbf,
                const __bf16* __restrict__ w2, const float* __restrict__ conv_b,
                __bf16* __restrict__ cbuf)
{
    __shared__ __align__(16) __bf16 Pl[256*CP];   // 53.2 KB total
    __bf16* Bs = Pl;                              // staging: elems [0, 8960)
    int* tg = (int*)&Pl[2*SB];                    // 1024 ints: elems [8960,11008)
    const int b = blockIdx.x;
    const int tid = threadIdx.x;
    const int w = tid >> 6, lane = tid & 63;
    const int l15 = lane & 15, lk = lane >> 4;

    for (int i = tid; i < 1024; i += 512)
        tg[i] = ((i < SEQ) ? target[b*SEQ + i] : 8000) * 112;
    __syncthreads();

    const bool st = tid < 448;
    const int sr  = tid & 31;    // k-row within 32-tile
    const int sch = tid >> 5;    // col chunk 0..13 (8 cols each)

    uint4 sv;
    auto stage_load = [&](int p) {
        if (!st) return;
        sv = *(const uint4*)((const ushort*)embbf + tg[p*32 + sr] + sch*8);
    };
    auto stage_write = [&](int buf) {
        if (!st) return;
        const __bf16* s8 = (const __bf16*)&sv;
        __bf16* base = &Bs[buf*SB + (sch*8)*40 + sr];
#pragma unroll
        for (int j = 0; j < 8; j++) base[j*40] = s8[j];
    };

    f32x4 acc[7][2];
#pragma unroll
    for (int i = 0; i < 7; i++) {
        acc[i][0] = (f32x4){0.f,0.f,0.f,0.f};
        acc[i][1] = (f32x4){0.f,0.f,0.f,0.f};
    }

    const __bf16* w2w0 = w2 + (size_t)(w*32 + l15)*1024 + lk*8;
    const __bf16* w2w1 = w2w0 + (size_t)16*1024;

    stage_load(0);
    stage_write(0);
    int cur = 0;
    for (int p = 0; p < 32; ++p) {
        __syncthreads();
        if (p+1 < 32) stage_load(p+1);
        bf16x8 bf0 = *(const bf16x8*)(w2w0 + p*32);
        bf16x8 bf1 = *(const bf16x8*)(w2w1 + p*32);
        const __bf16* bsc = Bs + cur*SB + lk*8;
        __builtin_amdgcn_s_setprio(1);
#pragma unroll
        for (int mt = 0; mt < 7; mt++) {
            bf16x8 af = *(const bf16x8*)(bsc + (mt*16 + l15)*40);
            acc[mt][0] = __builtin_amdgcn_mfma_f32_16x16x32_bf16(af, bf0, acc[mt][0], 0, 0, 0);
            acc[mt][1] = __builtin_amdgcn_mfma_f32_16x16x32_bf16(af, bf1, acc[mt][1], 0, 0, 0);
        }
        __builtin_amdgcn_s_setprio(0);
        if (p+1 < 32) stage_write(cur^1);
        cur ^= 1;
    }

    __syncthreads();   // staging + tg dead; write P over it
#pragma unroll
    for (int mt = 0; mt < 7; mt++) {
#pragma unroll
        for (int nt = 0; nt < 2; nt++) {
            int op = w*32 + nt*16 + l15;
            int c0 = mt*16 + lk*4;
            if (c0 >= 100) continue;   // cols >= 100 never read
            __bf16 o4[4];
#pragma unroll
            for (int rr = 0; rr < 4; rr++) o4[rr] = (__bf16)acc[mt][nt][rr];
            *(uint2*)&Pl[op*CP + c0] = *(uint2*)o4;
        }
    }
    __syncthreads();

    // shift-add: thread (o = tid&31, tg16 = tid>>5): 6 t's each
    {
        int o = tid & 31, tg16 = tid >> 5;
        float cb = conv_b[o];
#pragma unroll
        for (int j = 0; j < 6; j++) {
            int t = tg16*6 + j;
            if (t >= CLEN) continue;
            float s = cb;
#pragma unroll
            for (int k = 0; k < 8; k++)
                s += (float)Pl[(k*32 + o)*CP + t + k];
            cbuf[(size_t)b*2976 + o*CLEN + t] = (__bf16)s;
        }
    }
}

// ---------------------------------------------------------------------------
// mlp3: out[r] = dot(o2bf[r,0:512], w) + b   (wave per row)
// ---------------------------------------------------------------------------
__global__ __launch_bounds__(256)
void mlp3_dot(const __bf16* __restrict__ o2, const float* __restrict__ w,
              const float* __restrict__ bias, float* __restrict__ out)
{
    int row = blockIdx.x*4 + (threadIdx.x >> 6);
    int lane = threadIdx.x & 63;
    bf16x8 v = *(const bf16x8*)(o2 + (size_t)row*512 + lane*8);
    float4 w0 = *(const float4*)(w + lane*8);
    float4 w1 = *(const float4*)(w + lane*8 + 4);
    float s = (float)v[0]*w0.x + (float)v[1]*w0.y + (float)v[2]*w0.z + (float)v[3]*w0.w
            + (float)v[4]*w1.x + (float)v[5]*w1.y + (float)v[6]*w1.z + (float)v[7]*w1.w;
#pragma unroll
    for (int off = 32; off > 0; off >>= 1) s += __shfl_down(s, off);
    if (lane == 0) out[row] = s + bias[0];
}

// ---------------------------------------------------------------------------
extern "C" void kernel_launch(void* const* d_in, const int* in_sizes, int n_in,
                              void* d_out, int out_size, void* d_ws, size_t ws_size,
                              hipStream_t stream)
{
    const float* x      = (const float*)d_in[0];
    const int*   ei     = (const int*)  d_in[1];
    const int*   batch  = (const int*)  d_in[2];
    const int*   target = (const int*)  d_in[3];
    const float* gat_w  = (const float*)d_in[4];
    const float* att_s  = (const float*)d_in[5];
    const float* att_d  = (const float*)d_in[6];
    const float* gat_b  = (const float*)d_in[7];
    const float* gcn_w  = (const float*)d_in[8];
    const float* gcn_b  = (const float*)d_in[9];
    const float* fcg1_w = (const float*)d_in[10];
    const float* fcg1_b = (const float*)d_in[11];
    const float* fcg2_w = (const float*)d_in[12];
    const float* fcg2_b = (const float*)d_in[13];
    const float* emb_w  = (const float*)d_in[14];
    const float* conv_w = (const float*)d_in[15];
    const float* conv_b = (const float*)d_in[16];
    const float* fcxt_w = (const float*)d_in[17];
    const float* fcxt_b = (const float*)d_in[18];
    const float* mlp1_w = (const float*)d_in[19];
    const float* mlp1_b = (const float*)d_in[20];
    const float* mlp2_w = (const float*)d_in[21];
    const float* mlp2_b = (const float*)d_in[22];
    const float* mlp3_w = (const float*)d_in[23];
    const float* mlp3_b = (const float*)d_in[24];
    float* out = (float*)d_out;

    char* ws = (char*)d_ws;
    size_t off = 0;
    auto alloc = [&](size_t bytes) -> char* {
        char* p = ws + off;
        off = (off + bytes + 255) & ~(size_t)255;
        return p;
    };
    __bf16* xhbf  = (__bf16*)alloc((size_t)NN*800*2);  // xh bf16, reused as hw bf16
    __bf16* g     = (__bf16*)alloc((size_t)NN*HD*2);
    char*  hbf_rg = alloc((size_t)NN*800*2);           // Abf -> hbf -> splitk partial
    __bf16* Abf   = (__bf16*)hbf_rg;
    __bf16* hbf   = (__bf16*)hbf_rg;
    float* partial= (float*)hbf_rg;                    // after hbf dead
    __bf16* wgat  = (__bf16*)alloc((size_t)896*96*2);
    __bf16* wgcn  = (__bf16*)alloc((size_t)896*800*2);
    __bf16* wg1   = (__bf16*)alloc((size_t)1536*1568*2);
    __bf16* wg2   = (__bf16*)alloc((size_t)128*1504*2);
    __bf16* wxt   = (__bf16*)alloc((size_t)128*2976*2);
    __bf16* wm1   = (__bf16*)alloc((size_t)1024*256*2);
    __bf16* wm2   = (__bf16*)alloc((size_t)512*1024*2);
    __bf16* convw2= (__bf16*)alloc((size_t)256*1024*2);
    __bf16* embbf = (__bf16*)alloc((size_t)8001*112*2);
    float* a_src  = (float*)alloc((size_t)NN*NH*4);
    float* a_dst  = (float*)alloc((size_t)NN*NH*4);
    int*   deg    = (int*)alloc((size_t)NN*4);
    int*   offs   = (int*)alloc((size_t)(NN+1)*4);
    int*   cursor = (int*)alloc((size_t)NN*4);
    int*   csr    = (int*)alloc((size_t)NT*4);
    float* dinv   = (float*)alloc((size_t)NN*4);
    int*   goffs  = (int*)alloc((size_t)(NG+1)*4);
    __bf16* dpool = (__bf16*)alloc((size_t)NG*1568*2);
    __bf16* d1bf  = (__bf16*)alloc((size_t)NG*1504*2);
    __bf16* cbuf  = (__bf16*)alloc((size_t)NG*NF*CLEN*2);
    __bf16* obuf  = (__bf16*)alloc((size_t)NG*256*2);
    __bf16* o1bf  = (__bf16*)alloc((size_t)NG*1024*2);
    __bf16* o2bf  = (__bf16*)alloc((size_t)NG*512*2);

    __bf16* hwbf = xhbf;   // xh dead after gat_agg

    hipMemsetAsync(deg, 0, (size_t)NN*4, stream);

    // --- input-only transforms ---
    preproc_all<<<dim3((unsigned)PRE_BLOCKS), 256, 0, stream>>>(
        emb_w, embbf, conv_w, convw2, x, Abf, batch, goffs);
    transpose_w<<<dim3(TRANS_BLOCKS), 256, 0, stream>>>(
        fcg1_w, wg1, gcn_w, wgcn, gat_w, wgat, fcg2_w, wg2,
        fcxt_w, wxt, mlp1_w, wm1, mlp2_w, wm2);

    // --- protein conv (independent of graph branch; run early) ---
    conv_gemm2<<<dim3(NG), 512, 0, stream>>>(target, embbf, convw2, conv_b, cbuf);

    // --- GAT linear: xh = x @ gat_w (Kp=96), bf16 out stride 800 ---
    gemm_mfma<false,false,true>
        <<<dim3(7, NN/128), 512, 0, stream>>>(Abf, wgat, nullptr, xhbf, NN, HD, 96, 800, 800);
    attn_logits<<<dim3((NN*NH+255)/256), 256, 0, stream>>>(xhbf, att_s, att_d, a_src, a_dst);

    // --- CSR (dinv folded into scan) ---
    edge_count  <<<dim3(NT/256), 256, 0, stream>>>(ei, deg);
    scan_kernel <<<1, 1024, 0, stream>>>(deg, offs, cursor, dinv);
    edge_scatter<<<dim3(NT/256), 256, 0, stream>>>(ei, cursor, csr);

    // --- GAT aggregate -> hbf (overwrites Abf; Abf dead) ---
    gat_agg<<<dim3(NN/4), 256, 0, stream>>>(xhbf, a_src, a_dst, gat_b, offs, csr, hbf);

    // --- GCN linear (bf16 out) + aggregate (bf16 g) ---
    gemm_mfma<false,false,true>
        <<<dim3(7, NN/128), 512, 0, stream>>>(hbf, wgcn, nullptr, hwbf, NN, HD, 800, 800, 800);
    gcn_agg<<<dim3(NN/4), 256, 0, stream>>>(hwbf, dinv, gcn_b, offs, csr, g);

    // --- pooling (goffs from preproc) ---
    pool_kernel<<<NG, 256, 0, stream>>>(g, goffs, dpool);

    // --- FC stack via split-K (partial aliases hbf; dead after gcn gemm) ---
    gemm_mfma_splitk<<<dim3(12, 4, 4), 256, 0, stream>>>(dpool, wg1, partial, NG, 1568, 1536, 13);
    reduce_splitk<true><<<dim3((NG*(1504/4)+255)/256), 256, 0, stream>>>(partial, fcg1_b, d1bf, NG, 1500, 1536, 4, 1504, 1504);
    gemm_mfma_splitk<<<dim3(1, 4, 12), 256, 0, stream>>>(d1bf, wg2, partial, NG, 1504, 128, 4);
    reduce_splitk<false><<<dim3((NG*32+255)/256), 256, 0, stream>>>(partial, fcg2_b, obuf, NG, 128, 128, 12, 256, 128);
    gemm_mfma_splitk<<<dim3(1, 4, 24), 256, 0, stream>>>(cbuf, wxt, partial, NG, 2976, 128, 4);
    reduce_splitk<false><<<dim3((NG*32+255)/256), 256, 0, stream>>>(partial, fcxt_b, obuf + 128, NG, 128, 128, 24, 256, 128);
    gemm_mfma_splitk<<<dim3(8, 4, 2), 256, 0, stream>>>(obuf, wm1, partial, NG, 256, 1024, 4);
    reduce_splitk<true><<<dim3((NG*256+255)/256), 256, 0, stream>>>(partial, mlp1_b, o1bf, NG, 1024, 1024, 2, 1024, 1024);
    gemm_mfma_splitk<<<dim3(4, 4, 8), 256, 0, stream>>>(o1bf, wm2, partial, NG, 1024, 512, 4);
    reduce_splitk<true><<<dim3((NG*128+255)/256), 256, 0, stream>>>(partial, mlp2_b, o2bf, NG, 512, 512, 8, 512, 512);

    mlp3_dot<<<dim3(NG/4), 256, 0, stream>>>(o2bf, mlp3_w, mlp3_b, out);
}